// Round 1
// 101.956 us; speedup vs baseline: 1.0812x; 1.0812x over previous
//
#include <hip/hip_runtime.h>

#define B_   4
#define Q_   256
#define C_   1024
#define H_   128
#define NEG  0.01f

// ---------------------------------------------------------------------------
// Kernel 1: hq[b,q,k] = sum_h query[b,q,h]*Ww[k,h]
//           hc[b,c,k] = sum_h context[b,c,h]*Ww[k,H+h] + bw[k]
// 4 rows per block, 128 threads (thread = output k) -> 1280 blocks,
// 2.5 waves/SIMD (was 1.25 at 8 rows/640 blocks) for latency hiding.
// Input rows are wave-uniform float4 loads; Ww row k is per-thread.
// ---------------------------------------------------------------------------
__global__ __launch_bounds__(128) void proj_kernel(
    const float* __restrict__ query, const float* __restrict__ context,
    const float* __restrict__ Ww, const float* __restrict__ bw,
    float* __restrict__ hq, float* __restrict__ hc)
{
    const int blk = blockIdx.x;
    const int k = threadIdx.x;
    const bool is_q = (blk < (B_ * Q_ / 4));              // 256 blocks for hq
    const int row0 = is_q ? (blk * 4) : ((blk - B_ * Q_ / 4) * 4);
    const float* __restrict__ in = is_q ? query : context;
    float* __restrict__ out = is_q ? hq : hc;

    const float4* __restrict__ Wrow =
        reinterpret_cast<const float4*>(Ww + k * (2 * H_) + (is_q ? 0 : H_));
    const float4* __restrict__ in4 =
        reinterpret_cast<const float4*>(in + row0 * H_);

    float acc[4] = {0.f, 0.f, 0.f, 0.f};
    #pragma unroll 4
    for (int h4 = 0; h4 < H_ / 4; ++h4) {
        const float4 w = Wrow[h4];
        #pragma unroll
        for (int r = 0; r < 4; ++r) {
            const float4 iv = in4[r * (H_ / 4) + h4];     // wave-uniform
            acc[r] += iv.x * w.x + iv.y * w.y + iv.z * w.z + iv.w * w.w;
        }
    }
    const float bias = is_q ? 0.f : bw[k];
    #pragma unroll
    for (int r = 0; r < 4; ++r)
        out[(row0 + r) * H_ + k] = acc[r] + bias;
}

// ---------------------------------------------------------------------------
// Kernel 2: per block = (b, 4 consecutive q). 512 threads (8 waves).
// b = blockIdx & 3 so consecutive blockIdx (round-robin over the 8 XCDs)
// pins each XCD to a single b: hc[b] + context[b] (~1 MB) stay L2-local.
//
// Phase 1 uses the exact identity leaky(x) = 0.505x + 0.495|x|:
//   score[q,c] = 0.505*(Dq[q] + dc[c]) + 0.495*sum_k Ws[k]*|hq+hc|
// Dq from an LDS-staged hq (once per block), dc fused in the k-loop.
// Inner loop: 2 VALU ops/element (v_add + v_fma with free abs modifier),
// all wave-uniform operands from LDS (no uniform global loads in the loop).
// bs omitted: softmax is shift-invariant, both outputs are post-softmax.
// ---------------------------------------------------------------------------
__global__ __launch_bounds__(512) void attn_kernel(
    const float* __restrict__ hq, const float* __restrict__ hc,
    const float* __restrict__ Ws, const float* __restrict__ context,
    float* __restrict__ outA, float* __restrict__ outP)
{
    const int b  = blockIdx.x & 3;           // XCD-aligned b mapping
    const int q0 = (blockIdx.x >> 2) * 4;    // 64 q-groups per b
    const int t  = threadIdx.x;
    const int wv = t >> 6;                   // wave id 0..7

    __shared__ float4 attn4_s[C_];           // 16 KiB: attn packed {q0..q3} per c
    __shared__ float  red[16 * 4 * H_];      // 32 KiB: phase-3 partials
    __shared__ float  s_hq[4][H_];           // 2 KiB: this block's 4 hq rows
    __shared__ float  s_ws[H_];              // 0.5 KiB
    __shared__ float  wred[8][4];
    __shared__ float  wsum[8][4];
    __shared__ float  dqp[2][4];

    // ---- stage hq rows + Ws into LDS
    {
        const int q = t >> 7, k = t & 127;
        s_hq[q][k] = hq[(b * Q_ + q0 + q) * H_ + k];
        if (t < H_) s_ws[t] = Ws[t];
    }
    __syncthreads();

    // ---- Dq[q] = dot(Ws, hq_row_q)  (2 waves, shuffle butterflies)
    if (t < 128) {
        float v[4];
        #pragma unroll
        for (int q = 0; q < 4; ++q) v[q] = s_ws[t] * s_hq[q][t];
        #pragma unroll
        for (int off = 32; off >= 1; off >>= 1) {
            #pragma unroll
            for (int q = 0; q < 4; ++q) v[q] += __shfl_xor(v[q], off, 64);
        }
        if ((t & 63) == 0) {
            #pragma unroll
            for (int q = 0; q < 4; ++q) dqp[t >> 6][q] = v[q];
        }
    }
    __syncthreads();
    float Dq[4];
    #pragma unroll
    for (int q = 0; q < 4; ++q) Dq[q] = dqp[0][q] + dqp[1][q];

    // ---- phase 1: abs-part + dc over c in {t, t+512}
    const int c0 = t, c1 = t + 512;
    const float4* __restrict__ ws4 = reinterpret_cast<const float4*>(s_ws);
    const float4* __restrict__ hcp0 =
        reinterpret_cast<const float4*>(hc + (b * C_ + c0) * H_);
    const float4* __restrict__ hcp1 =
        reinterpret_cast<const float4*>(hc + (b * C_ + c1) * H_);

    float sabs[4][2] = {{0.f,0.f},{0.f,0.f},{0.f,0.f},{0.f,0.f}};
    float dc0 = 0.f, dc1 = 0.f;
    #pragma unroll 4
    for (int k0 = 0; k0 < H_ / 4; ++k0) {
        const float4 wsv = ws4[k0];                        // LDS broadcast
        float4 hqv[4];
        #pragma unroll
        for (int q = 0; q < 4; ++q)
            hqv[q] = reinterpret_cast<const float4*>(s_hq[q])[k0];  // LDS broadcast
        const float4 h0 = hcp0[k0];
        const float4 h1 = hcp1[k0];
        dc0 += wsv.x * h0.x + wsv.y * h0.y + wsv.z * h0.z + wsv.w * h0.w;
        dc1 += wsv.x * h1.x + wsv.y * h1.y + wsv.z * h1.z + wsv.w * h1.w;
        #pragma unroll
        for (int q = 0; q < 4; ++q) {
            sabs[q][0] += wsv.x * fabsf(hqv[q].x + h0.x)
                        + wsv.y * fabsf(hqv[q].y + h0.y)
                        + wsv.z * fabsf(hqv[q].z + h0.z)
                        + wsv.w * fabsf(hqv[q].w + h0.w);
            sabs[q][1] += wsv.x * fabsf(hqv[q].x + h1.x)
                        + wsv.y * fabsf(hqv[q].y + h1.y)
                        + wsv.z * fabsf(hqv[q].z + h1.z)
                        + wsv.w * fabsf(hqv[q].w + h1.w);
        }
    }
    float s[4][2];
    #pragma unroll
    for (int q = 0; q < 4; ++q) {
        s[q][0] = 0.505f * (Dq[q] + dc0) + 0.495f * sabs[q][0];
        s[q][1] = 0.505f * (Dq[q] + dc1) + 0.495f * sabs[q][1];
    }

    // ---- phase 2: softmax over the 1024 c per q row
    float m[4];
    #pragma unroll
    for (int q = 0; q < 4; ++q) {
        float v = fmaxf(s[q][0], s[q][1]);
        #pragma unroll
        for (int off = 32; off >= 1; off >>= 1)
            v = fmaxf(v, __shfl_xor(v, off, 64));
        m[q] = v;
    }
    if ((t & 63) == 0) {
        #pragma unroll
        for (int q = 0; q < 4; ++q) wred[wv][q] = m[q];
    }
    __syncthreads();
    #pragma unroll
    for (int q = 0; q < 4; ++q) {
        float v = wred[0][q];
        #pragma unroll
        for (int i = 1; i < 8; ++i) v = fmaxf(v, wred[i][q]);
        m[q] = v;
    }
    float e[4][2], p[4];
    #pragma unroll
    for (int q = 0; q < 4; ++q) {
        e[q][0] = __expf(s[q][0] - m[q]);
        e[q][1] = __expf(s[q][1] - m[q]);
        float v = e[q][0] + e[q][1];
        #pragma unroll
        for (int off = 32; off >= 1; off >>= 1)
            v += __shfl_xor(v, off, 64);
        p[q] = v;
    }
    if ((t & 63) == 0) {
        #pragma unroll
        for (int q = 0; q < 4; ++q) wsum[wv][q] = p[q];
    }
    __syncthreads();
    float rS[4];
    #pragma unroll
    for (int q = 0; q < 4; ++q) {
        float S = wsum[0][q];
        #pragma unroll
        for (int i = 1; i < 8; ++i) S += wsum[i][q];
        rS[q] = 1.0f / S;
    }
    float a0[4], a1[4];
    #pragma unroll
    for (int q = 0; q < 4; ++q) {
        a0[q] = e[q][0] * rS[q];
        a1[q] = e[q][1] * rS[q];
    }
    attn4_s[c0] = make_float4(a0[0], a0[1], a0[2], a0[3]);
    attn4_s[c1] = make_float4(a1[0], a1[1], a1[2], a1[3]);
    #pragma unroll
    for (int q = 0; q < 4; ++q) {
        outP[(b * Q_ + q0 + q) * C_ + c0] = a0[q];
        outP[(b * Q_ + q0 + q) * C_ + c1] = a1[q];
    }
    __syncthreads();

    // ---- phase 3: attn_output[q][h] = sum_c attn[q][c]*context[b][c][h]
    const float4* __restrict__ ctx4 = reinterpret_cast<const float4*>(context);
    const int hg   = t & 31;      // float4 h-chunk: h = hg*4..hg*4+3
    const int crep = t >> 5;      // 16 c-chunks of 64
    float4 acc[4] = {{0,0,0,0},{0,0,0,0},{0,0,0,0},{0,0,0,0}};
    const int cb = crep * 64;
    #pragma unroll 4
    for (int cc = 0; cc < 64; ++cc) {
        const int c = cb + cc;
        const float4 a4 = attn4_s[c];
        const float4 xv = ctx4[(b * C_ + c) * (H_ / 4) + hg];
        acc[0].x += a4.x * xv.x; acc[0].y += a4.x * xv.y; acc[0].z += a4.x * xv.z; acc[0].w += a4.x * xv.w;
        acc[1].x += a4.y * xv.x; acc[1].y += a4.y * xv.y; acc[1].z += a4.y * xv.z; acc[1].w += a4.y * xv.w;
        acc[2].x += a4.z * xv.x; acc[2].y += a4.z * xv.y; acc[2].z += a4.z * xv.z; acc[2].w += a4.z * xv.w;
        acc[3].x += a4.w * xv.x; acc[3].y += a4.w * xv.y; acc[3].z += a4.w * xv.z; acc[3].w += a4.w * xv.w;
    }
    float4* red4 = reinterpret_cast<float4*>(red);
    #pragma unroll
    for (int q = 0; q < 4; ++q)
        red4[(crep * 4 + q) * 32 + hg] = acc[q];
    __syncthreads();
    {
        const int q = t >> 7, h = t & 127;
        float v = 0.f;
        #pragma unroll
        for (int cr = 0; cr < 16; ++cr)
            v += red[(cr * 4 + q) * H_ + h];
        outA[(b * Q_ + q0 + q) * H_ + h] = v;
    }
}

extern "C" void kernel_launch(void* const* d_in, const int* in_sizes, int n_in,
                              void* d_out, int out_size, void* d_ws, size_t ws_size,
                              hipStream_t stream) {
    const float* query   = (const float*)d_in[0];
    const float* context = (const float*)d_in[1];
    const float* Ww      = (const float*)d_in[2];
    const float* bw      = (const float*)d_in[3];
    const float* Ws      = (const float*)d_in[4];
    // d_in[5] (bs) intentionally unused: softmax is shift-invariant and both
    // outputs are post-softmax quantities.

    float* outA = (float*)d_out;                 // attn_output: B*Q*H
    float* outP = outA + B_ * Q_ * H_;           // attn:        B*Q*C

    float* hq = (float*)d_ws;                    // B*Q*H floats (512 KB)
    float* hc = hq + B_ * Q_ * H_;               // B*C*H floats (2 MB)

    hipLaunchKernelGGL(proj_kernel, dim3(1280), dim3(128), 0, stream,
                       query, context, Ww, bw, hq, hc);
    hipLaunchKernelGGL(attn_kernel, dim3(256), dim3(512), 0, stream,
                       hq, hc, Ws, context, outA, outP);
}